// Round 7
// baseline (1353.861 us; speedup 1.0000x reference)
//
#include <hip/hip_runtime.h>

// EncoderGRUODE: B=256, T=512, D_IN=64, H=128
// R9: DS-pipe attack (R7/R8 nulls localized the bottleneck).
//   Accounting: R6-R8 issue ~38 DS wave-ops/lane-stream/step (22 b128 reads +
//   9 ds_swizzle + writes) x 8 waves ~= 300 DS ops/CU/step ~= 2900cy of the
//   5166cy step on the ONE per-CU LDS pipe; swizzles also add ~100cy latency
//   at the end of every phase chain. VALU is per-SIMD (4x parallel) - trade
//   DS for VALU.
// Changes vs R8 (schedule/numerics class unchanged):
//   - 16 lanes x 4 rows per group (8-float col slice per row): per-step
//     ds_read_b128 22 -> 11.
//   - all-DPP split-reduce (NO ds_swizzle): xor1=quad_perm 0xB1, xor2=0x4E,
//     xor4-exchange=ROW_HALF_MIRROR 0x141 (always crosses bit2 in an 8-half),
//     xor8-exchange=ROW_ROR:8 0x128 (exactly lane^8 within 16-lane rows).
//     Lane (b2,b3) ends owning row 4g + 2*b2 + b3.
// Predicted: conflicts ~0, VALUBusy% rises ~72-80, dur 1102 -> ~820-920us.
//   Falsifier: flat dur => DS not limiter => VALU inflation real; attack insts.

#define NB    256
#define TB    512
#define TSTEP 512
#define DIN   64
#define HD    128

typedef float v2f __attribute__((ext_vector_type(2)));

__device__ __forceinline__ float fast_tanh(float v) {
    float e = __expf(2.0f * v);
    return 1.0f - 2.0f / (e + 1.0f);
}
__device__ __forceinline__ float fast_sigmoid(float v) {
    return 1.0f / (1.0f + __expf(-v));
}

// LDS-only block barrier (R7): drain lgkm, sync; vmcnt stays outstanding.
__device__ __forceinline__ void sync_lds() {
    asm volatile("s_waitcnt lgkmcnt(0)" ::: "memory");
    __builtin_amdgcn_s_barrier();
    asm volatile("" ::: "memory");
}

template<int PAT>
__device__ __forceinline__ float dpp_xadd(float v) {
    return v + __int_as_float(__builtin_amdgcn_update_dpp(
        0, __float_as_int(v), PAT, 0xF, 0xF, true));
}
template<int PAT>
__device__ __forceinline__ float dpp_mov(float v) {
    return __int_as_float(__builtin_amdgcn_update_dpp(
        0, __float_as_int(v), PAT, 0xF, 0xF, true));
}
// butterfly xor1 + xor2 (quad-sum on every lane)
__device__ __forceinline__ float qred(float v) {
    v = dpp_xadd<0xB1>(v);
    return dpp_xadd<0x4E>(v);
}
// split-reduce 4 row-partials over 16 lanes, all-DPP.
// Lane (b2,b3) returns total of row index 2*b2 + b3 (within the group's 4).
__device__ __forceinline__ float red16x4(float p0, float p1, float p2, float p3,
                                         bool b2, bool b3) {
    p0 = qred(p0); p1 = qred(p1); p2 = qred(p2); p3 = qred(p3);
    float u  = b2 ? p2 : p0;     // keep row (b2?2:0)
    float us = b2 ? p0 : p2;     // send the other
    float v  = b2 ? p3 : p1;     // keep row (b2?3:1)
    float vs = b2 ? p1 : p3;
    u += dpp_mov<0x141>(us);     // ROW_HALF_MIRROR: other quad (bit2 flip)
    v += dpp_mov<0x141>(vs);
    float w  = b3 ? v : u;       // keep row (2*b2 + b3)
    float ws = b3 ? u : v;
    w += dpp_mov<0x128>(ws);     // ROW_ROR:8 == lane^8 within 16-lane row
    return w;
}
// split-reduce 2 row-partials over 16 lanes; lane b3 returns row b3's total.
__device__ __forceinline__ float red16x2(float p0, float p1, bool b3) {
    p0 = qred(p0); p1 = qred(p1);
    p0 += dpp_mov<0x141>(p0);
    p1 += dpp_mov<0x141>(p1);
    float w  = b3 ? p1 : p0;
    float ws = b3 ? p0 : p1;
    w += dpp_mov<0x128>(ws);
    return w;
}

__global__ __launch_bounds__(TB, 2) void gruode_kernel(
    const float* __restrict__ x,         // [B, T, DIN]
    const float* __restrict__ tp,        // [B, T] (row 0 used)
    const int*   __restrict__ samp_mask, // [T]
    const float* __restrict__ W_ih,      // [3H, DIN]
    const float* __restrict__ W_hh,      // [3H, H]
    const float* __restrict__ b_ih,      // [3H]
    const float* __restrict__ b_hh,      // [3H]
    const float* __restrict__ W_node,    // [H, H]
    const float* __restrict__ b_node,    // [H]
    const float* __restrict__ W_out,     // [DIN, H]
    const float* __restrict__ b_out,     // [DIN]
    float*       __restrict__ out)       // [B*T, DIN]
{
    const int t    = threadIdx.x;
    const int b    = blockIdx.x;
    const int g    = t >> 4;              // group 0..31 (4 hidden rows each)
    const int ks2  = t & 15;              // 8-float strided col slice 0..15
    const bool b2  = (ks2 & 4)  != 0;
    const bool b3  = (ks2 & 8)  != 0;
    const int jm   = 4*g + (b2 ? 2 : 0) + (b3 ? 1 : 0);  // my hidden row
    const bool own = (ks2 & 3) == 0;      // one writer lane per row
    const int jo   = 2*g + (b3 ? 1 : 0);  // my out row (64 total)
    const bool oown= (ks2 & 7) == 0;      // one writer lane per out row

    __shared__ __align__(16) float sh_h [HD];
    __shared__ __align__(16) float sh_t0[HD];
    __shared__ __align__(16) float sh_t1[HD];
    __shared__ __align__(16) float sh_in[DIN];
    __shared__ __align__(16) float sh_po[DIN];
    __shared__ float sh_dt[TSTEP];
    __shared__ int   sh_mk[TSTEP];

    const float4* Wn4  = (const float4*)W_node;  // [128][32 f4]
    const float4* Whh4 = (const float4*)W_hh;    // [384][32 f4]
    const float4* Wih4 = (const float4*)W_ih;    // [384][16 f4]
    const float4* Wo4  = (const float4*)W_out;   // [64][32 f4]

    // ---- weights -> registers: 4 rows x strided 8-float slice ----
    // Lane owns float4 cols {ks2, 16+ks2} of each of its 4 rows.
    v2f Wn[16], Whr[16], Whz[16], Whn[16];
    #pragma unroll
    for (int r = 0; r < 4; ++r) {
        const int row = 4*g + r;
        float4 a, c;
        a = Wn4 [row*32 + ks2];      Wn [4*r+0]=(v2f){a.x,a.y}; Wn [4*r+1]=(v2f){a.z,a.w};
        c = Wn4 [row*32 + 16 + ks2]; Wn [4*r+2]=(v2f){c.x,c.y}; Wn [4*r+3]=(v2f){c.z,c.w};
        a = Whh4[(0*HD+row)*32 + ks2];      Whr[4*r+0]=(v2f){a.x,a.y}; Whr[4*r+1]=(v2f){a.z,a.w};
        c = Whh4[(0*HD+row)*32 + 16 + ks2]; Whr[4*r+2]=(v2f){c.x,c.y}; Whr[4*r+3]=(v2f){c.z,c.w};
        a = Whh4[(1*HD+row)*32 + ks2];      Whz[4*r+0]=(v2f){a.x,a.y}; Whz[4*r+1]=(v2f){a.z,a.w};
        c = Whh4[(1*HD+row)*32 + 16 + ks2]; Whz[4*r+2]=(v2f){c.x,c.y}; Whz[4*r+3]=(v2f){c.z,c.w};
        a = Whh4[(2*HD+row)*32 + ks2];      Whn[4*r+0]=(v2f){a.x,a.y}; Whn[4*r+1]=(v2f){a.z,a.w};
        c = Whh4[(2*HD+row)*32 + 16 + ks2]; Whn[4*r+2]=(v2f){c.x,c.y}; Whn[4*r+3]=(v2f){c.z,c.w};
    }
    v2f Wir[8], Wiz[8], Win[8];
    #pragma unroll
    for (int r = 0; r < 4; ++r) {
        const int row = 4*g + r;
        float4 a;
        a = Wih4[(0*HD+row)*16 + ks2]; Wir[2*r]=(v2f){a.x,a.y}; Wir[2*r+1]=(v2f){a.z,a.w};
        a = Wih4[(1*HD+row)*16 + ks2]; Wiz[2*r]=(v2f){a.x,a.y}; Wiz[2*r+1]=(v2f){a.z,a.w};
        a = Wih4[(2*HD+row)*16 + ks2]; Win[2*r]=(v2f){a.x,a.y}; Win[2*r+1]=(v2f){a.z,a.w};
    }
    v2f Wo[8];
    #pragma unroll
    for (int o = 0; o < 2; ++o) {
        const int row = 2*g + o;
        float4 a = Wo4[row*32 + ks2];
        float4 c = Wo4[row*32 + 16 + ks2];
        Wo[4*o+0]=(v2f){a.x,a.y}; Wo[4*o+1]=(v2f){a.z,a.w};
        Wo[4*o+2]=(v2f){c.x,c.y}; Wo[4*o+3]=(v2f){c.z,c.w};
    }
    // Pin: opaque to rematerialization (prevents L2 re-fetch).
    #pragma unroll
    for (int i = 0; i < 16; ++i) {
        asm volatile("" : "+v"(Wn[i]));  asm volatile("" : "+v"(Whr[i]));
        asm volatile("" : "+v"(Whz[i])); asm volatile("" : "+v"(Whn[i]));
    }
    #pragma unroll
    for (int i = 0; i < 8; ++i) {
        asm volatile("" : "+v"(Wir[i])); asm volatile("" : "+v"(Wiz[i]));
        asm volatile("" : "+v"(Win[i])); asm volatile("" : "+v"(Wo[i]));
    }

    // per-row biases for my row jm; out bias for my out row jo
    const float bn_s = b_node[jm];
    const float br_s = b_ih[0*HD + jm] + b_hh[0*HD + jm];
    const float bz_s = b_ih[1*HD + jm] + b_hh[1*HD + jm];
    const float bi_s = b_ih[2*HD + jm];
    const float bh_s = b_hh[2*HD + jm];
    const float bo_s = b_out[jo];

    if (t < HD) sh_h[t] = 0.0f;
    {   // dt/mask tables -> LDS once (per-step reads are uniform broadcasts)
        float tc = tp[t];
        float tq = (t == 0) ? tc - 0.01f : tp[t - 1];
        sh_dt[t] = tc - tq;
        sh_mk[t] = samp_mask[t];
    }

    const float* xbase = x   + (size_t)b * TSTEP * DIN;
    float*       obase = out + (size_t)b * TSTEP * DIN;
    float xr = (t < DIN) ? xbase[t] : 0.0f;

    sync_lds();

    const float4* h4  = (const float4*)sh_h;
    const float4* t04 = (const float4*)sh_t0;
    const float4* t14 = (const float4*)sh_t1;
    const float4* in4 = (const float4*)sh_in;

    // load my 8-float slice of a 128-float LDS vector (2 ds_read_b128)
    auto lds2 = [&](const float4* buf, v2f& l0, v2f& u0, v2f& l1, v2f& u1) {
        float4 v0 = buf[ks2], v1 = buf[16 + ks2];
        l0 = (v2f){v0.x, v0.y}; u0 = (v2f){v0.z, v0.w};
        l1 = (v2f){v1.x, v1.y}; u1 = (v2f){v1.z, v1.w};
    };
    // 4-row dot partials against the slice
    auto dot4 = [&](const v2f (&W)[16], v2f l0, v2f u0, v2f l1, v2f u1,
                    float (&p)[4]) {
        #pragma unroll
        for (int r = 0; r < 4; ++r) {
            v2f a = W[4*r]*l0 + W[4*r+1]*u0 + W[4*r+2]*l1 + W[4*r+3]*u1;
            p[r] = a.x + a.y;
        }
    };

    float hj = 0.0f;   // my row's h (all 4 lanes of row jm carry it)

    #pragma unroll 1
    for (int s = 0; s < TSTEP; ++s) {
        const float dt = sh_dt[s];
        const int   mc = sh_mk[s];
        float k1, k2, k3;

        // ---- P1: k1 dot + out matvec sharing the same sh_h slice loads ----
        {
            v2f l0,u0,l1,u1; lds2(h4, l0,u0,l1,u1);
            float p[4]; dot4(Wn, l0,u0,l1,u1, p);
            v2f ao0 = Wo[0]*l0 + Wo[1]*u0 + Wo[2]*l1 + Wo[3]*u1;
            v2f ao1 = Wo[4]*l0 + Wo[5]*u0 + Wo[6]*l1 + Wo[7]*u1;
            k1 = fast_tanh(red16x4(p[0],p[1],p[2],p[3], b2,b3) + bn_s);
            float o = red16x2(ao0.x + ao0.y, ao1.x + ao1.y, b3) + bo_s;
            if (oown) {
                sh_po[jo] = o;                   // prev_out for this step
                if (s > 0) obase[(size_t)(s - 1) * DIN + jo] = o;
            }
            if (own) sh_t0[jm] = fmaf(0.5f * dt, k1, hj);
        }
        sync_lds();                                        // B1

        // ---- P2: build input vec; k2 dot; prefetch next-step x ----
        if (t < DIN) sh_in[t] = mc ? xr : sh_po[t];
        {
            v2f l0,u0,l1,u1; lds2(t04, l0,u0,l1,u1);
            float p[4]; dot4(Wn, l0,u0,l1,u1, p);
            k2 = fast_tanh(red16x4(p[0],p[1],p[2],p[3], b2,b3) + bn_s);
            if (own) sh_t1[jm] = fmaf(0.5f * dt, k2, hj);
        }
        {
            const int sn = (s + 1 < TSTEP) ? s + 1 : s;
            if (t < DIN) xr = xbase[(size_t)sn * DIN + t];
        }
        sync_lds();                                        // B2

        // ---- P3: k3 dot + input-gate partials (reduced later / carried) ----
        float cr[4], cz[4], cn[4];
        {
            v2f l0,u0,l1,u1; lds2(t14, l0,u0,l1,u1);
            float p[4]; dot4(Wn, l0,u0,l1,u1, p);
            k3 = fast_tanh(red16x4(p[0],p[1],p[2],p[3], b2,b3) + bn_s);

            float4 vi = in4[ks2];                 // my 4-float slice of input
            v2f li = (v2f){vi.x, vi.y}, ui = (v2f){vi.z, vi.w};
            #pragma unroll
            for (int r = 0; r < 4; ++r) {
                v2f a = Wir[2*r]*li + Wir[2*r+1]*ui;
                v2f c = Wiz[2*r]*li + Wiz[2*r+1]*ui;
                v2f d = Win[2*r]*li + Win[2*r+1]*ui;
                cr[r] = a.x + a.y;  cz[r] = c.x + c.y;  cn[r] = d.x + d.y;
            }
            if (own) sh_t0[jm] = fmaf(dt, k3, hj);
        }
        sync_lds();                                        // B3

        // ---- P4: k4 dot; h_ode ----
        float hode;
        {
            v2f l0,u0,l1,u1; lds2(t04, l0,u0,l1,u1);
            float p[4]; dot4(Wn, l0,u0,l1,u1, p);
            float k4 = fast_tanh(red16x4(p[0],p[1],p[2],p[3], b2,b3) + bn_s);
            hode = fmaf(dt * (1.0f / 6.0f),
                        (k1 + 2.0f * k2) + (2.0f * k3 + k4), hj);
            if (own) sh_t1[jm] = hode;                     // t1 = h_ode vector
        }
        sync_lds();                                        // B4

        // ---- P5: hidden-gate dots + combine (input partials folded) ----
        {
            v2f l0,u0,l1,u1; lds2(t14, l0,u0,l1,u1);
            float ar[4], az[4], an[4];
            dot4(Whr, l0,u0,l1,u1, ar);
            dot4(Whz, l0,u0,l1,u1, az);
            dot4(Whn, l0,u0,l1,u1, an);
            float r_  = red16x4(ar[0]+cr[0], ar[1]+cr[1], ar[2]+cr[2], ar[3]+cr[3], b2,b3);
            float z_  = red16x4(az[0]+cz[0], az[1]+cz[1], az[2]+cz[2], az[3]+cz[3], b2,b3);
            float hn  = red16x4(an[0], an[1], an[2], an[3], b2,b3);
            float cns = red16x4(cn[0], cn[1], cn[2], cn[3], b2,b3);

            float rr = fast_sigmoid(r_ + br_s);
            float zz = fast_sigmoid(z_ + bz_s);
            float nn = fast_tanh(fmaf(rr, hn + bh_s, cns + bi_s));
            float hnew = fmaf(zz, hode - nn, nn);          // (1-z)n + z*h_ode
            hj = hnew;
            if (own) sh_h[jm] = hnew;
        }
        sync_lds();                                        // B5
    }

    // ---- epilogue: out[T-1] from final h ----
    {
        v2f l0,u0,l1,u1; lds2(h4, l0,u0,l1,u1);
        v2f ao0 = Wo[0]*l0 + Wo[1]*u0 + Wo[2]*l1 + Wo[3]*u1;
        v2f ao1 = Wo[4]*l0 + Wo[5]*u0 + Wo[6]*l1 + Wo[7]*u1;
        float o = red16x2(ao0.x + ao0.y, ao1.x + ao1.y, b3) + bo_s;
        if (oown) obase[(size_t)(TSTEP - 1) * DIN + jo] = o;
    }
}

extern "C" void kernel_launch(void* const* d_in, const int* in_sizes, int n_in,
                              void* d_out, int out_size, void* d_ws, size_t ws_size,
                              hipStream_t stream) {
    (void)in_sizes; (void)n_in; (void)d_ws; (void)ws_size; (void)out_size;
    const float* x      = (const float*)d_in[0];
    const float* tp     = (const float*)d_in[1];
    const int*   mask   = (const int*)  d_in[2];
    const float* W_ih   = (const float*)d_in[3];
    const float* W_hh   = (const float*)d_in[4];
    const float* b_ih   = (const float*)d_in[5];
    const float* b_hh   = (const float*)d_in[6];
    const float* W_node = (const float*)d_in[7];
    const float* b_node = (const float*)d_in[8];
    const float* W_out  = (const float*)d_in[9];
    const float* b_out  = (const float*)d_in[10];
    float* outp = (float*)d_out;

    gruode_kernel<<<NB, TB, 0, stream>>>(x, tp, mask, W_ih, W_hh, b_ih, b_hh,
                                         W_node, b_node, W_out, b_out, outp);
}

// Round 8
// 1246.777 us; speedup vs baseline: 1.0859x; 1.0859x over previous
//
#include <hip/hip_runtime.h>

// EncoderGRUODE: B=256, T=512, D_IN=64, H=128
// R10 = R6 structure + instruction-count attack.
//   Cross-round law: dur ~= 1.6 x VALU-busy-time (R2 577->1227, R6 682->1104,
//   R9 853->1354). VALU-issue-bound. Measured ~810 inst/wave/step vs ~470
//   if dots were packed => compiler scalarizes v2f math into 2x v_fma_f32.
//   Changes vs R6 (schedule, slicing, barriers identical):
//   1) inline-asm v_pk_fma_f32 / v_pk_mul_f32 for ALL dot kernels (dual-rate
//      packed fp32; per 128-row: 8 pk + 2 adds vs ~18 scalar).
//   2) ds_swizzle -> DPP ROW_HALF_MIRROR 0x141 in reductions (op-neutral,
//      removes 9 DS ops + lgkm latency from every phase chain; 0x141
//      correctness HW-verified in R9).
// Predicted: busy 682 -> ~540us, dur 1104 -> ~870-950us; conflicts 0.
//   Falsifier: flat => compiler already packed => pivot to schedule surgery.

#define NB    256
#define TB    512
#define TSTEP 512
#define DIN   64
#define HD    128

typedef float v2f __attribute__((ext_vector_type(2)));

__device__ __forceinline__ float fast_tanh(float v) {
    float e = __expf(2.0f * v);
    return 1.0f - 2.0f / (e + 1.0f);
}
__device__ __forceinline__ float fast_sigmoid(float v) {
    return 1.0f / (1.0f + __expf(-v));
}

// packed fp32 ops (dual-rate on CDNA2+). "v" constraint = arch-VGPR pair.
__device__ __forceinline__ v2f pk_mul(v2f a, v2f b) {
    v2f d;
    asm("v_pk_mul_f32 %0, %1, %2" : "=v"(d) : "v"(a), "v"(b));
    return d;
}
__device__ __forceinline__ v2f pk_fma(v2f a, v2f b, v2f c) {
    v2f d;
    asm("v_pk_fma_f32 %0, %1, %2, %3" : "=v"(d) : "v"(a), "v"(b), "v"(c));
    return d;
}

// LDS-only block barrier (R7): drain lgkm, sync; vmcnt stays outstanding.
__device__ __forceinline__ void sync_lds() {
    asm volatile("s_waitcnt lgkmcnt(0)" ::: "memory");
    __builtin_amdgcn_s_barrier();
    asm volatile("" ::: "memory");
}

template<int PAT>
__device__ __forceinline__ float dpp_xadd(float v) {
    return v + __int_as_float(__builtin_amdgcn_update_dpp(
        0, __float_as_int(v), PAT, 0xF, 0xF, true));
}
template<int PAT>
__device__ __forceinline__ float dpp_mov(float v) {
    return __int_as_float(__builtin_amdgcn_update_dpp(
        0, __float_as_int(v), PAT, 0xF, 0xF, true));
}
// 8-lane all-lanes reduction: xor1, xor2, then half-mirror (partner lives in
// the other quad; after xor1+xor2 all quad lanes hold the quad sum, so any
// other-quad partner works). Pure DPP - zero DS ops.
__device__ __forceinline__ float red8(float v) {
    v = dpp_xadd<0xB1>(v);
    v = dpp_xadd<0x4E>(v);
    return v + dpp_mov<0x141>(v);     // ROW_HALF_MIRROR
}
// reduce two row-partials over the 8-lane group for the price of one:
// lanes with low=true end with rowA total, low=false with rowB total.
__device__ __forceinline__ float red8_split(float pA, float pB, bool low) {
    pA = dpp_xadd<0xB1>(pA);  pB = dpp_xadd<0xB1>(pB);
    pA = dpp_xadd<0x4E>(pA);  pB = dpp_xadd<0x4E>(pB);
    float keep = low ? pA : pB;
    float send = low ? pB : pA;
    return keep + dpp_mov<0x141>(send);   // mirror partner in other quad
}

// packed 128-dot slice: 8 v2f terms -> 2 chains of 4 -> horizontal sum
__device__ __forceinline__ float dot8(const v2f (&w)[8],
                                      v2f l0, v2f u0, v2f l1, v2f u1,
                                      v2f l2, v2f u2, v2f l3, v2f u3) {
    v2f a = pk_mul(w[0], l0);
    a = pk_fma(w[1], u0, a);
    a = pk_fma(w[2], l1, a);
    a = pk_fma(w[3], u1, a);
    v2f b = pk_mul(w[4], l2);
    b = pk_fma(w[5], u2, b);
    b = pk_fma(w[6], l3, b);
    b = pk_fma(w[7], u3, b);
    v2f s = a + b;
    return s.x + s.y;
}
// packed 64-dot slice: 4 v2f terms
__device__ __forceinline__ float dot4i(const v2f (&w)[4],
                                       v2f l0, v2f u0, v2f l1, v2f u1) {
    v2f a = pk_mul(w[0], l0);
    a = pk_fma(w[1], u0, a);
    v2f b = pk_mul(w[2], l1);
    b = pk_fma(w[3], u1, b);
    v2f s = a + b;
    return s.x + s.y;
}

__global__ __launch_bounds__(TB, 2) void gruode_kernel(
    const float* __restrict__ x,         // [B, T, DIN]
    const float* __restrict__ tp,        // [B, T] (row 0 used)
    const int*   __restrict__ samp_mask, // [T]
    const float* __restrict__ W_ih,      // [3H, DIN]
    const float* __restrict__ W_hh,      // [3H, H]
    const float* __restrict__ b_ih,      // [3H]
    const float* __restrict__ b_hh,      // [3H]
    const float* __restrict__ W_node,    // [H, H]
    const float* __restrict__ b_node,    // [H]
    const float* __restrict__ W_out,     // [DIN, H]
    const float* __restrict__ b_out,     // [DIN]
    float*       __restrict__ out)       // [B*T, DIN]
{
    const int t    = threadIdx.x;
    const int b    = blockIdx.x;
    const int jp   = t >> 3;              // row-pair index 0..63 (also out row)
    const int ks   = t & 7;               // strided k-slice 0..7
    const bool low = (ks & 4) == 0;       // owns rowA (2jp) vs rowB (2jp+1)
    const int jm   = 2 * jp + (ks >> 2);  // my hidden row after split-reduce
    const bool own = (ks & 3) == 0;       // writer lane for row jm

    __shared__ __align__(16) float sh_h [HD];
    __shared__ __align__(16) float sh_t0[HD];
    __shared__ __align__(16) float sh_t1[HD];
    __shared__ __align__(16) float sh_in[DIN];
    __shared__ __align__(16) float sh_po[DIN];
    __shared__ float sh_dt[TSTEP];
    __shared__ int   sh_mk[TSTEP];

    const float4* Wn4  = (const float4*)W_node;  // [128][32 f4]
    const float4* Whh4 = (const float4*)W_hh;    // [384][32 f4]
    const float4* Wih4 = (const float4*)W_ih;    // [384][16 f4]
    const float4* Wo4  = (const float4*)W_out;   // [64][32 f4]

    // ---- weights -> registers: 2 rows x strided 16-float slice ----
    // Lane owns float4 columns {ii*8 + ks, ii=0..3} of 32 (RK4/GRU-h/out rows)
    // and {ii*8 + ks, ii=0..1} of 16 (input rows). Conflict-free read pattern.
    v2f WnA[8], WnB[8], WhrA[8], WhrB[8], WhzA[8], WhzB[8], WhnA[8], WhnB[8];
    #pragma unroll
    for (int ii = 0; ii < 4; ++ii) {
        float4 w;
        const int c = ii * 8 + ks;
        w = Wn4 [(2*jp  )*32 + c];        WnA [2*ii] = (v2f){w.x,w.y}; WnA [2*ii+1] = (v2f){w.z,w.w};
        w = Wn4 [(2*jp+1)*32 + c];        WnB [2*ii] = (v2f){w.x,w.y}; WnB [2*ii+1] = (v2f){w.z,w.w};
        w = Whh4[(0*HD + 2*jp  )*32 + c]; WhrA[2*ii] = (v2f){w.x,w.y}; WhrA[2*ii+1] = (v2f){w.z,w.w};
        w = Whh4[(0*HD + 2*jp+1)*32 + c]; WhrB[2*ii] = (v2f){w.x,w.y}; WhrB[2*ii+1] = (v2f){w.z,w.w};
        w = Whh4[(1*HD + 2*jp  )*32 + c]; WhzA[2*ii] = (v2f){w.x,w.y}; WhzA[2*ii+1] = (v2f){w.z,w.w};
        w = Whh4[(1*HD + 2*jp+1)*32 + c]; WhzB[2*ii] = (v2f){w.x,w.y}; WhzB[2*ii+1] = (v2f){w.z,w.w};
        w = Whh4[(2*HD + 2*jp  )*32 + c]; WhnA[2*ii] = (v2f){w.x,w.y}; WhnA[2*ii+1] = (v2f){w.z,w.w};
        w = Whh4[(2*HD + 2*jp+1)*32 + c]; WhnB[2*ii] = (v2f){w.x,w.y}; WhnB[2*ii+1] = (v2f){w.z,w.w};
    }
    v2f WirA[4], WirB[4], WizA[4], WizB[4], WinA[4], WinB[4], Wo[8];
    #pragma unroll
    for (int ii = 0; ii < 2; ++ii) {
        float4 w;
        const int c = ii * 8 + ks;
        w = Wih4[(0*HD + 2*jp  )*16 + c]; WirA[2*ii] = (v2f){w.x,w.y}; WirA[2*ii+1] = (v2f){w.z,w.w};
        w = Wih4[(0*HD + 2*jp+1)*16 + c]; WirB[2*ii] = (v2f){w.x,w.y}; WirB[2*ii+1] = (v2f){w.z,w.w};
        w = Wih4[(1*HD + 2*jp  )*16 + c]; WizA[2*ii] = (v2f){w.x,w.y}; WizA[2*ii+1] = (v2f){w.z,w.w};
        w = Wih4[(1*HD + 2*jp+1)*16 + c]; WizB[2*ii] = (v2f){w.x,w.y}; WizB[2*ii+1] = (v2f){w.z,w.w};
        w = Wih4[(2*HD + 2*jp  )*16 + c]; WinA[2*ii] = (v2f){w.x,w.y}; WinA[2*ii+1] = (v2f){w.z,w.w};
        w = Wih4[(2*HD + 2*jp+1)*16 + c]; WinB[2*ii] = (v2f){w.x,w.y}; WinB[2*ii+1] = (v2f){w.z,w.w};
    }
    #pragma unroll
    for (int ii = 0; ii < 4; ++ii) {      // out row jp, same strided slice as k1
        float4 w = Wo4[jp*32 + ii*8 + ks];
        Wo[2*ii] = (v2f){w.x,w.y}; Wo[2*ii+1] = (v2f){w.z,w.w};
    }
    // Pin: opaque to rematerialization (prevents L2 re-fetch).
    #pragma unroll
    for (int ii = 0; ii < 8; ++ii) {
        asm volatile("" : "+v"(WnA[ii]));  asm volatile("" : "+v"(WnB[ii]));
        asm volatile("" : "+v"(WhrA[ii])); asm volatile("" : "+v"(WhrB[ii]));
        asm volatile("" : "+v"(WhzA[ii])); asm volatile("" : "+v"(WhzB[ii]));
        asm volatile("" : "+v"(WhnA[ii])); asm volatile("" : "+v"(WhnB[ii]));
        asm volatile("" : "+v"(Wo[ii]));
    }
    #pragma unroll
    for (int ii = 0; ii < 4; ++ii) {
        asm volatile("" : "+v"(WirA[ii])); asm volatile("" : "+v"(WirB[ii]));
        asm volatile("" : "+v"(WizA[ii])); asm volatile("" : "+v"(WizB[ii]));
        asm volatile("" : "+v"(WinA[ii])); asm volatile("" : "+v"(WinB[ii]));
    }

    // per-row biases for my row jm; out bias for row jp
    const float bn_s = b_node[jm];
    const float br_s = b_ih[0*HD + jm] + b_hh[0*HD + jm];
    const float bz_s = b_ih[1*HD + jm] + b_hh[1*HD + jm];
    const float bi_s = b_ih[2*HD + jm];
    const float bh_s = b_hh[2*HD + jm];
    const float bo   = b_out[jp];

    if (t < HD) sh_h[t] = 0.0f;
    {   // dt/mask tables -> LDS once (per-step reads are uniform broadcasts)
        float tc = tp[t];
        float tq = (t == 0) ? tc - 0.01f : tp[t - 1];
        sh_dt[t] = tc - tq;
        sh_mk[t] = samp_mask[t];
    }

    const float* xbase = x   + (size_t)b * TSTEP * DIN;
    float*       obase = out + (size_t)b * TSTEP * DIN;
    float xr = (t < DIN) ? xbase[t] : 0.0f;

    sync_lds();

    const float4* h4  = (const float4*)sh_h;
    const float4* t04 = (const float4*)sh_t0;
    const float4* t14 = (const float4*)sh_t1;
    const float4* in4 = (const float4*)sh_in;

    float hj = 0.0f;   // my row's h (meaningful on owner lanes)

    #pragma unroll 1
    for (int s = 0; s < TSTEP; ++s) {
        const float dt = sh_dt[s];
        const int   mc = sh_mk[s];
        float k1, k2, k3;

        // ---- P1: k1 dot + out matvec sharing the same sh_h loads ----
        {
            float4 v0 = h4[ks], v1 = h4[8+ks], v2 = h4[16+ks], v3 = h4[24+ks];
            v2f l0 = {v0.x,v0.y}, u0 = {v0.z,v0.w};
            v2f l1 = {v1.x,v1.y}, u1 = {v1.z,v1.w};
            v2f l2 = {v2.x,v2.y}, u2 = {v2.z,v2.w};
            v2f l3 = {v3.x,v3.y}, u3 = {v3.z,v3.w};
            float sA = dot8(WnA, l0,u0,l1,u1,l2,u2,l3,u3);
            float sB = dot8(WnB, l0,u0,l1,u1,l2,u2,l3,u3);
            float so = dot8(Wo,  l0,u0,l1,u1,l2,u2,l3,u3);
            k1 = fast_tanh(red8_split(sA, sB, low) + bn_s);
            float o = red8(so) + bo;             // = h(s-1)@Wo^T + bo
            if (ks == 0) {
                sh_po[jp] = o;                   // prev_out for this step
                if (s > 0) obase[(size_t)(s - 1) * DIN + jp] = o;
            }
            if (own) sh_t0[jm] = fmaf(0.5f * dt, k1, hj);
        }
        sync_lds();                                        // B1

        // ---- P2: build input vec; k2 dot; prefetch next-step x ----
        if (t < DIN) sh_in[t] = mc ? xr : sh_po[t];
        {
            float4 v0 = t04[ks], v1 = t04[8+ks], v2 = t04[16+ks], v3 = t04[24+ks];
            v2f l0 = {v0.x,v0.y}, u0 = {v0.z,v0.w};
            v2f l1 = {v1.x,v1.y}, u1 = {v1.z,v1.w};
            v2f l2 = {v2.x,v2.y}, u2 = {v2.z,v2.w};
            v2f l3 = {v3.x,v3.y}, u3 = {v3.z,v3.w};
            float sA = dot8(WnA, l0,u0,l1,u1,l2,u2,l3,u3);
            float sB = dot8(WnB, l0,u0,l1,u1,l2,u2,l3,u3);
            k2 = fast_tanh(red8_split(sA, sB, low) + bn_s);
            if (own) sh_t1[jm] = fmaf(0.5f * dt, k2, hj);
        }
        {
            const int sn = (s + 1 < TSTEP) ? s + 1 : s;
            if (t < DIN) xr = xbase[(size_t)sn * DIN + t];
        }
        sync_lds();                                        // B2

        // ---- P3: k3 dot + input-gate partial dots (reduction deferred) ----
        float crA, crB, czA, czB, cnA, cnB;
        {
            float4 v0 = t14[ks], v1 = t14[8+ks], v2 = t14[16+ks], v3 = t14[24+ks];
            v2f l0 = {v0.x,v0.y}, u0 = {v0.z,v0.w};
            v2f l1 = {v1.x,v1.y}, u1 = {v1.z,v1.w};
            v2f l2 = {v2.x,v2.y}, u2 = {v2.z,v2.w};
            v2f l3 = {v3.x,v3.y}, u3 = {v3.z,v3.w};
            float sA = dot8(WnA, l0,u0,l1,u1,l2,u2,l3,u3);
            float sB = dot8(WnB, l0,u0,l1,u1,l2,u2,l3,u3);
            k3 = fast_tanh(red8_split(sA, sB, low) + bn_s);

            float4 w0 = in4[ks], w1 = in4[8 + ks];
            v2f li0 = {w0.x,w0.y}, ui0 = {w0.z,w0.w};
            v2f li1 = {w1.x,w1.y}, ui1 = {w1.z,w1.w};
            crA = dot4i(WirA, li0,ui0,li1,ui1);
            crB = dot4i(WirB, li0,ui0,li1,ui1);
            czA = dot4i(WizA, li0,ui0,li1,ui1);
            czB = dot4i(WizB, li0,ui0,li1,ui1);
            cnA = dot4i(WinA, li0,ui0,li1,ui1);
            cnB = dot4i(WinB, li0,ui0,li1,ui1);

            if (own) sh_t0[jm] = fmaf(dt, k3, hj);
        }
        sync_lds();                                        // B3

        // ---- P4: k4 dot; h_ode ----
        float hode;
        {
            float4 v0 = t04[ks], v1 = t04[8+ks], v2 = t04[16+ks], v3 = t04[24+ks];
            v2f l0 = {v0.x,v0.y}, u0 = {v0.z,v0.w};
            v2f l1 = {v1.x,v1.y}, u1 = {v1.z,v1.w};
            v2f l2 = {v2.x,v2.y}, u2 = {v2.z,v2.w};
            v2f l3 = {v3.x,v3.y}, u3 = {v3.z,v3.w};
            float sA = dot8(WnA, l0,u0,l1,u1,l2,u2,l3,u3);
            float sB = dot8(WnB, l0,u0,l1,u1,l2,u2,l3,u3);
            float k4 = fast_tanh(red8_split(sA, sB, low) + bn_s);
            hode = fmaf(dt * (1.0f / 6.0f),
                        (k1 + 2.0f * k2) + (2.0f * k3 + k4), hj);
            if (own) sh_t1[jm] = hode;                     // t1 = h_ode vector
        }
        sync_lds();                                        // B4

        // ---- P5: hidden-gate dots + combine (input partials folded) ----
        {
            float4 v0 = t14[ks], v1 = t14[8+ks], v2 = t14[16+ks], v3 = t14[24+ks];
            v2f l0 = {v0.x,v0.y}, u0 = {v0.z,v0.w};
            v2f l1 = {v1.x,v1.y}, u1 = {v1.z,v1.w};
            v2f l2 = {v2.x,v2.y}, u2 = {v2.z,v2.w};
            v2f l3 = {v3.x,v3.y}, u3 = {v3.z,v3.w};
            float arA = dot8(WhrA, l0,u0,l1,u1,l2,u2,l3,u3);
            float arB = dot8(WhrB, l0,u0,l1,u1,l2,u2,l3,u3);
            float azA = dot8(WhzA, l0,u0,l1,u1,l2,u2,l3,u3);
            float azB = dot8(WhzB, l0,u0,l1,u1,l2,u2,l3,u3);
            float anA = dot8(WhnA, l0,u0,l1,u1,l2,u2,l3,u3);
            float anB = dot8(WhnB, l0,u0,l1,u1,l2,u2,l3,u3);

            float r_  = red8_split(arA + crA, arB + crB, low);
            float z_  = red8_split(azA + czA, azB + czB, low);
            float hn  = red8_split(anA, anB, low);
            float in_ = red8_split(cnA, cnB, low);

            float rr = fast_sigmoid(r_ + br_s);
            float zz = fast_sigmoid(z_ + bz_s);
            float nn = fast_tanh(fmaf(rr, hn + bh_s, in_ + bi_s));
            float hnew = fmaf(zz, hode - nn, nn);          // (1-z)n + z*h_ode
            hj = hnew;                                      // valid on owners
            if (own) sh_h[jm] = hnew;
        }
        sync_lds();                                        // B5
    }

    // ---- epilogue: out[T-1] from final h ----
    {
        float4 v0 = h4[ks], v1 = h4[8+ks], v2 = h4[16+ks], v3 = h4[24+ks];
        v2f l0 = {v0.x,v0.y}, u0 = {v0.z,v0.w};
        v2f l1 = {v1.x,v1.y}, u1 = {v1.z,v1.w};
        v2f l2 = {v2.x,v2.y}, u2 = {v2.z,v2.w};
        v2f l3 = {v3.x,v3.y}, u3 = {v3.z,v3.w};
        float so = dot8(Wo, l0,u0,l1,u1,l2,u2,l3,u3);
        float o = red8(so) + bo;
        if (ks == 0) obase[(size_t)(TSTEP - 1) * DIN + jp] = o;
    }
}

extern "C" void kernel_launch(void* const* d_in, const int* in_sizes, int n_in,
                              void* d_out, int out_size, void* d_ws, size_t ws_size,
                              hipStream_t stream) {
    (void)in_sizes; (void)n_in; (void)d_ws; (void)ws_size; (void)out_size;
    const float* x      = (const float*)d_in[0];
    const float* tp     = (const float*)d_in[1];
    const int*   mask   = (const int*)  d_in[2];
    const float* W_ih   = (const float*)d_in[3];
    const float* W_hh   = (const float*)d_in[4];
    const float* b_ih   = (const float*)d_in[5];
    const float* b_hh   = (const float*)d_in[6];
    const float* W_node = (const float*)d_in[7];
    const float* b_node = (const float*)d_in[8];
    const float* W_out  = (const float*)d_in[9];
    const float* b_out  = (const float*)d_in[10];
    float* outp = (float*)d_out;

    gruode_kernel<<<NB, TB, 0, stream>>>(x, tp, mask, W_ih, W_hh, b_ih, b_hh,
                                         W_node, b_node, W_out, b_out, outp);
}

// Round 9
// 1104.538 us; speedup vs baseline: 1.2257x; 1.1288x over previous
//
#include <hip/hip_runtime.h>

// EncoderGRUODE: B=256, T=512, D_IN=64, H=128
// R11 = R7 (best, 1099us) + amdgpu_num_vgpr(256). Single change.
//   Ledger: dur ~= 1.6 x VALU-busy across R2-R10; best busy ~680us (R6/R7).
//   Source-level count ~490 inst/wave/step vs ~825 measured; gap ~335 ~=
//   2.3 x 144 weight-uses/step => weights AGPR-resident (128 arch + 128 acc
//   split of the unified file), every use pays accvgpr traffic. FETCH=18MB
//   rules out L2 re-fetch; R8's waves_per_eu knob failed to move VGPR_Count
//   (knob failure, not theory failure). R10's pk-asm regressed (asm operand
//   moves + scheduling barriers) - reverted.
//   Fix: request 256 arch VGPRs directly. At grid-capped 2 waves/SIMD the
//   budget is exactly 256/wave; weights(192)+working(~55) fit, zero shuttle.
// Predicted: VGPR_Count -> ~230-256 (readout!). If shuttle real: busy
//   682->~500us, dur 1099->~830-920. VGPR flat => attribute ignored.
//   VGPR up + dur flat => shuttle theory dead, structure near floor.

#define NB    256
#define TB    512
#define TSTEP 512
#define DIN   64
#define HD    128

typedef float v2f __attribute__((ext_vector_type(2)));

__device__ __forceinline__ float fast_tanh(float v) {
    float e = __expf(2.0f * v);
    return 1.0f - 2.0f / (e + 1.0f);
}
__device__ __forceinline__ float fast_sigmoid(float v) {
    return 1.0f / (1.0f + __expf(-v));
}

// LDS-only block barrier: drain lgkm (our ds_writes visible), sync, and fence
// code motion on both sides. Does NOT drain vmcnt (global ops stay in flight).
__device__ __forceinline__ void sync_lds() {
    asm volatile("s_waitcnt lgkmcnt(0)" ::: "memory");
    __builtin_amdgcn_s_barrier();
    asm volatile("" ::: "memory");
}

template<int PAT>
__device__ __forceinline__ float dpp_xadd(float v) {
    return v + __int_as_float(__builtin_amdgcn_update_dpp(
        0, __float_as_int(v), PAT, 0xF, 0xF, true));
}
template<int OFF>
__device__ __forceinline__ float swz(float v) {
    return __int_as_float(__builtin_amdgcn_ds_swizzle(__float_as_int(v), OFF));
}
// plain 8-lane all-lanes reduction (xor1, xor2, xor4)
__device__ __forceinline__ float red8(float v) {
    v = dpp_xadd<0xB1>(v);
    v = dpp_xadd<0x4E>(v);
    return v + swz<0x101F>(v);
}
// reduce two row-partials over the 8-lane group for the price of one:
// lanes with low=true end with rowA total, low=false with rowB total.
__device__ __forceinline__ float red8_split(float pA, float pB, bool low) {
    pA = dpp_xadd<0xB1>(pA);  pB = dpp_xadd<0xB1>(pB);
    pA = dpp_xadd<0x4E>(pA);  pB = dpp_xadd<0x4E>(pB);
    float keep = low ? pA : pB;
    float send = low ? pB : pA;
    return keep + swz<0x101F>(send);
}

__global__ __launch_bounds__(TB, 2)
__attribute__((amdgpu_num_vgpr(256)))
void gruode_kernel(
    const float* __restrict__ x,         // [B, T, DIN]
    const float* __restrict__ tp,        // [B, T] (row 0 used)
    const int*   __restrict__ samp_mask, // [T]
    const float* __restrict__ W_ih,      // [3H, DIN]
    const float* __restrict__ W_hh,      // [3H, H]
    const float* __restrict__ b_ih,      // [3H]
    const float* __restrict__ b_hh,      // [3H]
    const float* __restrict__ W_node,    // [H, H]
    const float* __restrict__ b_node,    // [H]
    const float* __restrict__ W_out,     // [DIN, H]
    const float* __restrict__ b_out,     // [DIN]
    float*       __restrict__ out)       // [B*T, DIN]
{
    const int t    = threadIdx.x;
    const int b    = blockIdx.x;
    const int jp   = t >> 3;              // row-pair index 0..63 (also out row)
    const int ks   = t & 7;               // strided k-slice 0..7
    const bool low = (ks & 4) == 0;       // owns rowA (2jp) vs rowB (2jp+1)
    const int jm   = 2 * jp + (ks >> 2);  // my hidden row after split-reduce
    const bool own = (ks & 3) == 0;       // writer lane for row jm

    __shared__ __align__(16) float sh_h [HD];
    __shared__ __align__(16) float sh_t0[HD];
    __shared__ __align__(16) float sh_t1[HD];
    __shared__ __align__(16) float sh_in[DIN];
    __shared__ __align__(16) float sh_po[DIN];
    __shared__ float sh_dt[TSTEP];
    __shared__ int   sh_mk[TSTEP];

    const float4* Wn4  = (const float4*)W_node;  // [128][32 f4]
    const float4* Whh4 = (const float4*)W_hh;    // [384][32 f4]
    const float4* Wih4 = (const float4*)W_ih;    // [384][16 f4]
    const float4* Wo4  = (const float4*)W_out;   // [64][32 f4]

    // ---- weights -> registers: 2 rows x strided 16-float slice ----
    // Lane owns float4 columns {ii*8 + ks, ii=0..3} of 32 (RK4/GRU-h/out rows)
    // and {ii*8 + ks, ii=0..1} of 16 (input rows). Conflict-free read pattern.
    v2f WnA[8], WnB[8], WhrA[8], WhrB[8], WhzA[8], WhzB[8], WhnA[8], WhnB[8];
    #pragma unroll
    for (int ii = 0; ii < 4; ++ii) {
        float4 w;
        const int c = ii * 8 + ks;
        w = Wn4 [(2*jp  )*32 + c];        WnA [2*ii] = (v2f){w.x,w.y}; WnA [2*ii+1] = (v2f){w.z,w.w};
        w = Wn4 [(2*jp+1)*32 + c];        WnB [2*ii] = (v2f){w.x,w.y}; WnB [2*ii+1] = (v2f){w.z,w.w};
        w = Whh4[(0*HD + 2*jp  )*32 + c]; WhrA[2*ii] = (v2f){w.x,w.y}; WhrA[2*ii+1] = (v2f){w.z,w.w};
        w = Whh4[(0*HD + 2*jp+1)*32 + c]; WhrB[2*ii] = (v2f){w.x,w.y}; WhrB[2*ii+1] = (v2f){w.z,w.w};
        w = Whh4[(1*HD + 2*jp  )*32 + c]; WhzA[2*ii] = (v2f){w.x,w.y}; WhzA[2*ii+1] = (v2f){w.z,w.w};
        w = Whh4[(1*HD + 2*jp+1)*32 + c]; WhzB[2*ii] = (v2f){w.x,w.y}; WhzB[2*ii+1] = (v2f){w.z,w.w};
        w = Whh4[(2*HD + 2*jp  )*32 + c]; WhnA[2*ii] = (v2f){w.x,w.y}; WhnA[2*ii+1] = (v2f){w.z,w.w};
        w = Whh4[(2*HD + 2*jp+1)*32 + c]; WhnB[2*ii] = (v2f){w.x,w.y}; WhnB[2*ii+1] = (v2f){w.z,w.w};
    }
    v2f WirA[4], WirB[4], WizA[4], WizB[4], WinA[4], WinB[4], Wo[8];
    #pragma unroll
    for (int ii = 0; ii < 2; ++ii) {
        float4 w;
        const int c = ii * 8 + ks;
        w = Wih4[(0*HD + 2*jp  )*16 + c]; WirA[2*ii] = (v2f){w.x,w.y}; WirA[2*ii+1] = (v2f){w.z,w.w};
        w = Wih4[(0*HD + 2*jp+1)*16 + c]; WirB[2*ii] = (v2f){w.x,w.y}; WirB[2*ii+1] = (v2f){w.z,w.w};
        w = Wih4[(1*HD + 2*jp  )*16 + c]; WizA[2*ii] = (v2f){w.x,w.y}; WizA[2*ii+1] = (v2f){w.z,w.w};
        w = Wih4[(1*HD + 2*jp+1)*16 + c]; WizB[2*ii] = (v2f){w.x,w.y}; WizB[2*ii+1] = (v2f){w.z,w.w};
        w = Wih4[(2*HD + 2*jp  )*16 + c]; WinA[2*ii] = (v2f){w.x,w.y}; WinA[2*ii+1] = (v2f){w.z,w.w};
        w = Wih4[(2*HD + 2*jp+1)*16 + c]; WinB[2*ii] = (v2f){w.x,w.y}; WinB[2*ii+1] = (v2f){w.z,w.w};
    }
    #pragma unroll
    for (int ii = 0; ii < 4; ++ii) {      // out row jp, same strided slice as k1
        float4 w = Wo4[jp*32 + ii*8 + ks];
        Wo[2*ii] = (v2f){w.x,w.y}; Wo[2*ii+1] = (v2f){w.z,w.w};
    }
    // Pin: opaque to rematerialization (prevents L2 re-fetch).
    #pragma unroll
    for (int ii = 0; ii < 8; ++ii) {
        asm volatile("" : "+v"(WnA[ii]));  asm volatile("" : "+v"(WnB[ii]));
        asm volatile("" : "+v"(WhrA[ii])); asm volatile("" : "+v"(WhrB[ii]));
        asm volatile("" : "+v"(WhzA[ii])); asm volatile("" : "+v"(WhzB[ii]));
        asm volatile("" : "+v"(WhnA[ii])); asm volatile("" : "+v"(WhnB[ii]));
        asm volatile("" : "+v"(Wo[ii]));
    }
    #pragma unroll
    for (int ii = 0; ii < 4; ++ii) {
        asm volatile("" : "+v"(WirA[ii])); asm volatile("" : "+v"(WirB[ii]));
        asm volatile("" : "+v"(WizA[ii])); asm volatile("" : "+v"(WizB[ii]));
        asm volatile("" : "+v"(WinA[ii])); asm volatile("" : "+v"(WinB[ii]));
    }

    // per-row biases for my row jm; out bias for row jp
    const float bn_s = b_node[jm];
    const float br_s = b_ih[0*HD + jm] + b_hh[0*HD + jm];
    const float bz_s = b_ih[1*HD + jm] + b_hh[1*HD + jm];
    const float bi_s = b_ih[2*HD + jm];
    const float bh_s = b_hh[2*HD + jm];
    const float bo   = b_out[jp];

    if (t < HD) sh_h[t] = 0.0f;
    {   // dt/mask tables -> LDS once (per-step reads are uniform broadcasts)
        float tc = tp[t];
        float tq = (t == 0) ? tc - 0.01f : tp[t - 1];
        sh_dt[t] = tc - tq;
        sh_mk[t] = samp_mask[t];
    }

    const float* xbase = x   + (size_t)b * TSTEP * DIN;
    float*       obase = out + (size_t)b * TSTEP * DIN;
    float xr = (t < DIN) ? xbase[t] : 0.0f;

    sync_lds();

    const float4* h4  = (const float4*)sh_h;
    const float4* t04 = (const float4*)sh_t0;
    const float4* t14 = (const float4*)sh_t1;
    const float4* in4 = (const float4*)sh_in;

    // 2-row strided dot over a 128-float LDS vector: for fixed ii, the wave's
    // 8 float4 addrs cover all 32 banks once (conflict-free).
    auto dot2 = [&](const v2f (&wA)[8], const v2f (&wB)[8], const float4* buf,
                    float& rA, float& rB) {
        v2f aA = {0.f,0.f}, bA = {0.f,0.f}, aB = {0.f,0.f}, bB = {0.f,0.f};
        #pragma unroll
        for (int ii = 0; ii < 4; ++ii) {
            float4 v = buf[ii*8 + ks];
            v2f lo = {v.x, v.y}, hi = {v.z, v.w};
            aA += wA[2*ii] * lo;  bA += wA[2*ii+1] * hi;
            aB += wB[2*ii] * lo;  bB += wB[2*ii+1] * hi;
        }
        v2f sA = aA + bA, sB = aB + bB;
        rA = sA.x + sA.y;  rB = sB.x + sB.y;
    };

    float hj = 0.0f;   // my row's h (meaningful on owner lanes)

    #pragma unroll 1
    for (int s = 0; s < TSTEP; ++s) {
        const float dt = sh_dt[s];
        const int   mc = sh_mk[s];
        float k1, k2, k3;

        // ---- P1: k1 dot + out matvec sharing the same sh_h loads ----
        {
            float4 v0 = h4[ks], v1 = h4[8+ks], v2 = h4[16+ks], v3 = h4[24+ks];
            v2f l0 = {v0.x,v0.y}, u0 = {v0.z,v0.w};
            v2f l1 = {v1.x,v1.y}, u1 = {v1.z,v1.w};
            v2f l2 = {v2.x,v2.y}, u2 = {v2.z,v2.w};
            v2f l3 = {v3.x,v3.y}, u3 = {v3.z,v3.w};
            v2f aA = WnA[0]*l0 + WnA[1]*u0 + WnA[2]*l1 + WnA[3]*u1
                   + WnA[4]*l2 + WnA[5]*u2 + WnA[6]*l3 + WnA[7]*u3;
            v2f aB = WnB[0]*l0 + WnB[1]*u0 + WnB[2]*l1 + WnB[3]*u1
                   + WnB[4]*l2 + WnB[5]*u2 + WnB[6]*l3 + WnB[7]*u3;
            v2f ao = Wo[0]*l0 + Wo[1]*u0 + Wo[2]*l1 + Wo[3]*u1
                   + Wo[4]*l2 + Wo[5]*u2 + Wo[6]*l3 + Wo[7]*u3;
            k1 = fast_tanh(red8_split(aA.x + aA.y, aB.x + aB.y, low) + bn_s);
            float o = red8(ao.x + ao.y) + bo;   // = h(s-1)@Wo^T + bo
            if (ks == 0) {
                sh_po[jp] = o;                   // prev_out for this step
                if (s > 0) obase[(size_t)(s - 1) * DIN + jp] = o;
            }
            if (own) sh_t0[jm] = fmaf(0.5f * dt, k1, hj);
        }
        sync_lds();                                        // B1

        // ---- P2: build input vec; k2 dot; prefetch next-step x ----
        if (t < DIN) sh_in[t] = mc ? xr : sh_po[t];
        {
            float rA, rB;
            dot2(WnA, WnB, t04, rA, rB);
            k2 = fast_tanh(red8_split(rA, rB, low) + bn_s);
            if (own) sh_t1[jm] = fmaf(0.5f * dt, k2, hj);
        }
        {
            const int sn = (s + 1 < TSTEP) ? s + 1 : s;
            if (t < DIN) xr = xbase[(size_t)sn * DIN + t];
        }
        sync_lds();                                        // B2

        // ---- P3: k3 dot + input-gate partial dots (reduction deferred) ----
        float crA, crB, czA, czB, cnA, cnB;
        {
            float rA, rB;
            dot2(WnA, WnB, t14, rA, rB);
            k3 = fast_tanh(red8_split(rA, rB, low) + bn_s);

            float4 v0 = in4[ks], v1 = in4[8 + ks];
            v2f lo0 = {v0.x,v0.y}, hi0 = {v0.z,v0.w};
            v2f lo1 = {v1.x,v1.y}, hi1 = {v1.z,v1.w};
            v2f cr0 = WirA[0]*lo0 + WirA[1]*hi0 + WirA[2]*lo1 + WirA[3]*hi1;
            v2f cr1 = WirB[0]*lo0 + WirB[1]*hi0 + WirB[2]*lo1 + WirB[3]*hi1;
            v2f cz0 = WizA[0]*lo0 + WizA[1]*hi0 + WizA[2]*lo1 + WizA[3]*hi1;
            v2f cz1 = WizB[0]*lo0 + WizB[1]*hi0 + WizB[2]*lo1 + WizB[3]*hi1;
            v2f cn0 = WinA[0]*lo0 + WinA[1]*hi0 + WinA[2]*lo1 + WinA[3]*hi1;
            v2f cn1 = WinB[0]*lo0 + WinB[1]*hi0 + WinB[2]*lo1 + WinB[3]*hi1;
            crA = cr0.x + cr0.y;  crB = cr1.x + cr1.y;
            czA = cz0.x + cz0.y;  czB = cz1.x + cz1.y;
            cnA = cn0.x + cn0.y;  cnB = cn1.x + cn1.y;

            if (own) sh_t0[jm] = fmaf(dt, k3, hj);
        }
        sync_lds();                                        // B3

        // ---- P4: k4 dot; h_ode ----
        float hode;
        {
            float rA, rB;
            dot2(WnA, WnB, t04, rA, rB);
            float k4 = fast_tanh(red8_split(rA, rB, low) + bn_s);
            hode = fmaf(dt * (1.0f / 6.0f),
                        (k1 + 2.0f * k2) + (2.0f * k3 + k4), hj);
            if (own) sh_t1[jm] = hode;                     // t1 = h_ode vector
        }
        sync_lds();                                        // B4

        // ---- P5: hidden-gate dots + combine (input partials folded) ----
        {
            float4 v0 = t14[ks], v1 = t14[8+ks], v2 = t14[16+ks], v3 = t14[24+ks];
            v2f l0 = {v0.x,v0.y}, u0 = {v0.z,v0.w};
            v2f l1 = {v1.x,v1.y}, u1 = {v1.z,v1.w};
            v2f l2 = {v2.x,v2.y}, u2 = {v2.z,v2.w};
            v2f l3 = {v3.x,v3.y}, u3 = {v3.z,v3.w};
            v2f arA = WhrA[0]*l0 + WhrA[1]*u0 + WhrA[2]*l1 + WhrA[3]*u1
                    + WhrA[4]*l2 + WhrA[5]*u2 + WhrA[6]*l3 + WhrA[7]*u3;
            v2f arB = WhrB[0]*l0 + WhrB[1]*u0 + WhrB[2]*l1 + WhrB[3]*u1
                    + WhrB[4]*l2 + WhrB[5]*u2 + WhrB[6]*l3 + WhrB[7]*u3;
            v2f azA = WhzA[0]*l0 + WhzA[1]*u0 + WhzA[2]*l1 + WhzA[3]*u1
                    + WhzA[4]*l2 + WhzA[5]*u2 + WhzA[6]*l3 + WhzA[7]*u3;
            v2f azB = WhzB[0]*l0 + WhzB[1]*u0 + WhzB[2]*l1 + WhzB[3]*u1
                    + WhzB[4]*l2 + WhzB[5]*u2 + WhzB[6]*l3 + WhzB[7]*u3;
            v2f anA = WhnA[0]*l0 + WhnA[1]*u0 + WhnA[2]*l1 + WhnA[3]*u1
                    + WhnA[4]*l2 + WhnA[5]*u2 + WhnA[6]*l3 + WhnA[7]*u3;
            v2f anB = WhnB[0]*l0 + WhnB[1]*u0 + WhnB[2]*l1 + WhnB[3]*u1
                    + WhnB[4]*l2 + WhnB[5]*u2 + WhnB[6]*l3 + WhnB[7]*u3;

            float r_  = red8_split((arA.x + arA.y) + crA, (arB.x + arB.y) + crB, low);
            float z_  = red8_split((azA.x + azA.y) + czA, (azB.x + azB.y) + czB, low);
            float hn  = red8_split(anA.x + anA.y, anB.x + anB.y, low);
            float in_ = red8_split(cnA, cnB, low);

            float rr = fast_sigmoid(r_ + br_s);
            float zz = fast_sigmoid(z_ + bz_s);
            float nn = fast_tanh(fmaf(rr, hn + bh_s, in_ + bi_s));
            float hnew = fmaf(zz, hode - nn, nn);          // (1-z)n + z*h_ode
            hj = hnew;                                      // valid on owners
            if (own) sh_h[jm] = hnew;
        }
        sync_lds();                                        // B5
    }

    // ---- epilogue: out[T-1] from final h ----
    {
        float4 v0 = h4[ks], v1 = h4[8+ks], v2 = h4[16+ks], v3 = h4[24+ks];
        v2f l0 = {v0.x,v0.y}, u0 = {v0.z,v0.w};
        v2f l1 = {v1.x,v1.y}, u1 = {v1.z,v1.w};
        v2f l2 = {v2.x,v2.y}, u2 = {v2.z,v2.w};
        v2f l3 = {v3.x,v3.y}, u3 = {v3.z,v3.w};
        v2f ao = Wo[0]*l0 + Wo[1]*u0 + Wo[2]*l1 + Wo[3]*u1
               + Wo[4]*l2 + Wo[5]*u2 + Wo[6]*l3 + Wo[7]*u3;
        float o = red8(ao.x + ao.y) + bo;
        if (ks == 0) obase[(size_t)(TSTEP - 1) * DIN + jp] = o;
    }
}

extern "C" void kernel_launch(void* const* d_in, const int* in_sizes, int n_in,
                              void* d_out, int out_size, void* d_ws, size_t ws_size,
                              hipStream_t stream) {
    (void)in_sizes; (void)n_in; (void)d_ws; (void)ws_size; (void)out_size;
    const float* x      = (const float*)d_in[0];
    const float* tp     = (const float*)d_in[1];
    const int*   mask   = (const int*)  d_in[2];
    const float* W_ih   = (const float*)d_in[3];
    const float* W_hh   = (const float*)d_in[4];
    const float* b_ih   = (const float*)d_in[5];
    const float* b_hh   = (const float*)d_in[6];
    const float* W_node = (const float*)d_in[7];
    const float* b_node = (const float*)d_in[8];
    const float* W_out  = (const float*)d_in[9];
    const float* b_out  = (const float*)d_in[10];
    float* outp = (float*)d_out;

    gruode_kernel<<<NB, TB, 0, stream>>>(x, tp, mask, W_ih, W_hh, b_ih, b_hh,
                                         W_node, b_node, W_out, b_out, outp);
}